// Round 1
// baseline (223.012 us; speedup 1.0000x reference)
//
#include <hip/hip_runtime.h>
#include <hip/hip_bf16.h>

// ---------------------------------------------------------------------------
// WaveletNauralNet: 9-level DWT -> 8 band reconstructions (h: 2048x32768,
// linear in x1) -> relu -> W0 (181x32768) -> relu -> W1 (13x181) -> relu ->
// W2 (10x13).
//   K1: fused [per-row analysis (d2..d9 via LDS, single d1 drain)] +
//       [W0 fp32->fp16 convert] heterogeneous grid
//   K2 (THIS ROUND): per-(row,L) synthesis restructured:
//       - 16 outputs/thread stages (3x float4 windows, no 1-thread tails)
//       - fused stage pairs in registers: initpair16 (init+withcd from
//         global), pair16 (nocd+nocd), finpair16 (nocd+final) ->
//         barrier-stages 44 -> 25, LDS intermediate traffic ~halved
//       - XOR slot swizzle (slot ^ ((slot>>3)&7)) -> conflict-free b128
//         reads AND writes (prev: 32B-stride writes, 7.6M conflict cycles)
//       - __launch_bounds__(256,8): 8 blocks/CU (LDS 16.6KB/block)
//       Truncation semantics preserved: consumers read declared lengths,
//       truncated/garbage tail elements computed-but-never-stored.
//   K3: split-K MFMA fp16 GEMM, EXACT R8 form (BM=128,BN=192,BK=64,
//       nsplit=32, fp32 P). Staged-bytes floor ~53us, R8 ~90% of it.
//   K4: reduce partials + MLP layers 1..2 (R8 form)
// D rows repacked: DOFF multiples of 4 (16B-aligned float4 loads), DROW 4160.
// ---------------------------------------------------------------------------

typedef _Float16 f16x8 __attribute__((ext_vector_type(8)));
typedef _Float16 f16x4v __attribute__((ext_vector_type(4)));
typedef float f32x4 __attribute__((ext_vector_type(4)));

#define WV_THREADS 256
#define DROW 4160   // per-row float stride of packed d1..d9 (16B-aligned levels)
#define NSPLIT 32
#define KCHUNK 1024

// reconstruction filters
#define L0 0.23037781330885523f
#define L1 0.7148465705525415f
#define L2f 0.6308807679295904f
#define L3 -0.02798376941698385f
#define L4 -0.18703481171888114f
#define L5 0.030841381835986965f
#define L6 0.032883011666982945f
#define L7 -0.010597401784997278f

#define H0 -0.010597401784997278f
#define H1 -0.032883011666982945f
#define H2 0.030841381835986965f
#define H3 0.18703481171888114f
#define H4 -0.02798376941698385f
#define H5 -0.6308807679295904f
#define H6 0.7148465705525415f
#define H7 -0.23037781330885523f

__constant__ constexpr int cNL[10]   = {4096, 2051, 1029, 518, 262, 134, 70, 38, 22, 14};
// 16B-aligned packing; +pad between levels absorbs float4 window over-reads
__constant__ constexpr int cDOFF[10] = {0, 0, 2052, 3084, 3604, 3868, 4004, 4076, 4116, 4140};

__device__ __forceinline__ int ext_idx(int j, int n) {
  return (j < 6) ? (5 - j) : ((j < n + 6) ? (j - 6) : (2 * n + 5 - j));
}

// one DWT level, 2 outputs per thread, stride-1 lanes. (analysis, unchanged)
__device__ __forceinline__ void dwt2(const float* a, float* anext, float* d,
                                     int n, int m, bool store_a) {
  const int ng = (m + 1) >> 1;
  for (int g = threadIdx.x; g < ng; g += WV_THREADS) {
    float w[10];
    if (g >= 2 && 4 * g + 9 <= n + 5) {
      const float2* af = (const float2*)a + (2 * g - 3);
      float2 b0 = af[0], b1 = af[1], b2 = af[2], b3 = af[3], b4 = af[4];
      w[0] = b0.x; w[1] = b0.y; w[2] = b1.x; w[3] = b1.y; w[4] = b2.x;
      w[5] = b2.y; w[6] = b3.x; w[7] = b3.y; w[8] = b4.x; w[9] = b4.y;
    } else {
#pragma unroll
      for (int q = 0; q < 10; ++q) {
        int j = 4 * g + q;
        int jm = n + 12;
        if (j > jm) j = jm;
        w[q] = a[ext_idx(j, n)];
      }
    }
    float sl0 = w[0]*L0 + w[1]*L1 + w[2]*L2f + w[3]*L3 + w[4]*L4 + w[5]*L5 + w[6]*L6 + w[7]*L7;
    float sh0 = w[0]*H0 + w[1]*H1 + w[2]*H2  + w[3]*H3 + w[4]*H4 + w[5]*H5 + w[6]*H6 + w[7]*H7;
    float sl1 = w[2]*L0 + w[3]*L1 + w[4]*L2f + w[5]*L3 + w[6]*L4 + w[7]*L5 + w[8]*L6 + w[9]*L7;
    float sh1 = w[2]*H0 + w[3]*H1 + w[4]*H2  + w[5]*H3 + w[6]*H4 + w[7]*H5 + w[8]*H6 + w[9]*H7;
    if (2 * g + 1 < m) {
      if (store_a) *(float2*)(anext + 2 * g) = make_float2(sl0, sl1);
      *(float2*)(d + 2 * g) = make_float2(sh0, sh1);
    } else {
      if (store_a) anext[2 * g] = sl0;
      d[2 * g] = sh0;
    }
  }
}

// ---------------------------------------------------------------------------
// Swizzled LDS float4 slot accessors: slot u -> u ^ ((u>>3)&7). Bijective
// within each aligned 8-slot (128B) row; spreads 64B-blocked per-thread
// writes across all 8 float4-columns -> conflict-free ds_read/write_b128.
#define SWZ(u) ((u) ^ (((u) >> 3) & 7))
__device__ __forceinline__ const float4* lds4c(const float* b, int s) {
  return (const float4*)b + SWZ(s);
}
__device__ __forceinline__ float4* lds4(float* b, int s) {
  return (float4*)b + SWZ(s);
}

// Single IDWT step, 16 outputs (8 pairs) per thread.
//   e(p) = ca[p+3]L0+ca[p+2]L2+ca[p+1]L4+ca[p]L6 (+cd[.]H0..H6)
//   o(p) = ca[p+3]L1+ca[p+2]L3+ca[p+1]L5+ca[p]L7 (+cd[.]H1..H7)
// ca: LDS (swizzled); cd: global; FINAL: relu + f16 store.
template <bool HAS_CA, bool HAS_CD, bool FINAL, int N>
__device__ __forceinline__ void step16(const float* ca, const float* cd,
                                       float* outl, _Float16* outg) {
  constexpr int npair = N - 3;
  constexpr int ng = (npair + 7) >> 3;   // <= 256 for all uses
  const int t = threadIdx.x;
  if (t >= ng) return;
  float w[12], v[12];
  if constexpr (HAS_CA) {
    float4 a = *lds4c(ca, 2 * t), b = *lds4c(ca, 2 * t + 1), c = *lds4c(ca, 2 * t + 2);
    w[0]=a.x; w[1]=a.y; w[2]=a.z; w[3]=a.w; w[4]=b.x; w[5]=b.y; w[6]=b.z; w[7]=b.w;
    w[8]=c.x; w[9]=c.y; w[10]=c.z; w[11]=c.w;
  }
  if constexpr (HAS_CD) {
    const float4* p = (const float4*)(cd + 8 * t);  // 32B-aligned (DOFF mult of 4)
    float4 a = p[0], b = p[1], c = p[2];
    v[0]=a.x; v[1]=a.y; v[2]=a.z; v[3]=a.w; v[4]=b.x; v[5]=b.y; v[6]=b.z; v[7]=b.w;
    v[8]=c.x; v[9]=c.y; v[10]=c.z; v[11]=c.w;
  }
  float E[8], O[8];
#pragma unroll
  for (int pp = 0; pp < 8; ++pp) {   // global pair p = 8t+pp
    float e = 0.f, o = 0.f;
    if constexpr (HAS_CA) {
      e = w[pp+3]*L0 + w[pp+2]*L2f + w[pp+1]*L4 + w[pp]*L6;
      o = w[pp+3]*L1 + w[pp+2]*L3  + w[pp+1]*L5 + w[pp]*L7;
    }
    if constexpr (HAS_CD) {
      e += v[pp+3]*H0 + v[pp+2]*H2 + v[pp+1]*H4 + v[pp]*H6;
      o += v[pp+3]*H1 + v[pp+2]*H3 + v[pp+1]*H5 + v[pp]*H7;
    }
    E[pp] = e; O[pp] = o;
  }
  if constexpr (FINAL) {  // N=2051, npair=2048: all 256 threads full
    f16x8 h0, h1;
    h0[0]=(_Float16)fmaxf(E[0],0.f); h0[1]=(_Float16)fmaxf(O[0],0.f);
    h0[2]=(_Float16)fmaxf(E[1],0.f); h0[3]=(_Float16)fmaxf(O[1],0.f);
    h0[4]=(_Float16)fmaxf(E[2],0.f); h0[5]=(_Float16)fmaxf(O[2],0.f);
    h0[6]=(_Float16)fmaxf(E[3],0.f); h0[7]=(_Float16)fmaxf(O[3],0.f);
    h1[0]=(_Float16)fmaxf(E[4],0.f); h1[1]=(_Float16)fmaxf(O[4],0.f);
    h1[2]=(_Float16)fmaxf(E[5],0.f); h1[3]=(_Float16)fmaxf(O[5],0.f);
    h1[4]=(_Float16)fmaxf(E[6],0.f); h1[5]=(_Float16)fmaxf(O[6],0.f);
    h1[6]=(_Float16)fmaxf(E[7],0.f); h1[7]=(_Float16)fmaxf(O[7],0.f);
    *(f16x8*)(outg + 16 * t) = h0;
    *(f16x8*)(outg + 16 * t + 8) = h1;
  } else {
#pragma unroll
    for (int j = 0; j < 4; ++j) {
      const int p2 = 8 * t + 2 * j;
      if (p2 + 1 < npair) {
        *lds4(outl, 4 * t + j) = make_float4(E[2*j], O[2*j], E[2*j+1], O[2*j+1]);
      } else if (p2 < npair) {
        *(float2*)lds4(outl, 4 * t + j) = make_float2(E[2*j], O[2*j]);
      }
    }
  }
}

// Two fused no-cd stages from a 12-float window w (= cur[4t..4t+11]):
// stage1 intermediates r[qq] (global idx 8t+qq), stage2 outputs E/O pairs
// (global pair 8t+pp). Both stages use the L filter (no-cd idwt).
__device__ __forceinline__ void nocd2_core(const float w[12], float r[11],
                                           float E[8], float O[8]) {
#pragma unroll
  for (int h = 0; h < 6; ++h) {   // p1 = 4t+h
    float e = w[h+3]*L0 + w[h+2]*L2f + w[h+1]*L4 + w[h]*L6;
    float o = w[h+3]*L1 + w[h+2]*L3  + w[h+1]*L5 + w[h]*L7;
    r[2*h] = e;
    if (2*h + 1 < 11) r[2*h+1] = o;
  }
#pragma unroll
  for (int pp = 0; pp < 8; ++pp) {
    E[pp] = r[pp+3]*L0 + r[pp+2]*L2f + r[pp+1]*L4 + r[pp]*L6;
    O[pp] = r[pp+3]*L1 + r[pp+2]*L3  + r[pp+1]*L5 + r[pp]*L7;
  }
}

// PAIR: two no-cd IDWT steps fused, input LDS len N1 -> output LDS.
// N2 = truncated second-stage length (1030 -> 1029 per reference).
template <int N1>
__device__ __forceinline__ void pair16(const float* cur, float* outl) {
  constexpr int N2 = (2 * N1 - 6 == 1030) ? 1029 : (2 * N1 - 6);
  constexpr int np2 = N2 - 3;
  constexpr int ng = (np2 + 7) >> 3;
  const int t = threadIdx.x;
  if (t >= ng) return;
  float w[12];
  float4 a = *lds4c(cur, t), b = *lds4c(cur, t + 1), c = *lds4c(cur, t + 2);
  w[0]=a.x; w[1]=a.y; w[2]=a.z; w[3]=a.w; w[4]=b.x; w[5]=b.y; w[6]=b.z; w[7]=b.w;
  w[8]=c.x; w[9]=c.y; w[10]=c.z; w[11]=c.w;
  float r[11], E[8], O[8];
  nocd2_core(w, r, E, O);
#pragma unroll
  for (int j = 0; j < 4; ++j) {
    const int p2 = 8 * t + 2 * j;
    if (p2 + 1 < np2) {
      *lds4(outl, 4 * t + j) = make_float4(E[2*j], O[2*j], E[2*j+1], O[2*j+1]);
    } else if (p2 < np2) {
      *(float2*)lds4(outl, 4 * t + j) = make_float2(E[2*j], O[2*j]);
    }
  }
}

// FINPAIR: no-cd stage (N1=1029) fused with the final stage (2051 -> 4096,
// relu + f16). All 256 threads exactly full, no guards needed.
__device__ __forceinline__ void finpair16(const float* cur, _Float16* outg) {
  const int t = threadIdx.x;
  float w[12];
  float4 a = *lds4c(cur, t), b = *lds4c(cur, t + 1), c = *lds4c(cur, t + 2);
  w[0]=a.x; w[1]=a.y; w[2]=a.z; w[3]=a.w; w[4]=b.x; w[5]=b.y; w[6]=b.z; w[7]=b.w;
  w[8]=c.x; w[9]=c.y; w[10]=c.z; w[11]=c.w;
  float r[11], E[8], O[8];
  nocd2_core(w, r, E, O);
  f16x8 h0, h1;
  h0[0]=(_Float16)fmaxf(E[0],0.f); h0[1]=(_Float16)fmaxf(O[0],0.f);
  h0[2]=(_Float16)fmaxf(E[1],0.f); h0[3]=(_Float16)fmaxf(O[1],0.f);
  h0[4]=(_Float16)fmaxf(E[2],0.f); h0[5]=(_Float16)fmaxf(O[2],0.f);
  h0[6]=(_Float16)fmaxf(E[3],0.f); h0[7]=(_Float16)fmaxf(O[3],0.f);
  h1[0]=(_Float16)fmaxf(E[4],0.f); h1[1]=(_Float16)fmaxf(O[4],0.f);
  h1[2]=(_Float16)fmaxf(E[5],0.f); h1[3]=(_Float16)fmaxf(O[5],0.f);
  h1[4]=(_Float16)fmaxf(E[6],0.f); h1[5]=(_Float16)fmaxf(O[6],0.f);
  h1[6]=(_Float16)fmaxf(E[7],0.f); h1[7]=(_Float16)fmaxf(O[7],0.f);
  *(f16x8*)(outg + 16 * t) = h0;
  *(f16x8*)(outg + 16 * t + 8) = h1;
}

// INITPAIR: init (e/o from d_L via H filter) fused with the with-cd stage
// (r via L filter + d_{L-1} via H filter). Both operands straight from
// global dG; writes the with-cd output (len 2*(NLm1-3)) to LDS.
template <int NL, int NLm1>
__device__ __forceinline__ void initpair16(const float* cdL, const float* cdm,
                                           float* outl) {
  constexpr int np2 = NLm1 - 3;
  constexpr int ng = (np2 + 7) >> 3;
  const int t = threadIdx.x;
  if (t >= ng) return;
  float w[12];
  {
    const float4* p = (const float4*)(cdL + 4 * t);  // 16B-aligned
    float4 a = p[0], b = p[1], c = p[2];
    w[0]=a.x; w[1]=a.y; w[2]=a.z; w[3]=a.w; w[4]=b.x; w[5]=b.y; w[6]=b.z; w[7]=b.w;
    w[8]=c.x; w[9]=c.y; w[10]=c.z; w[11]=c.w;
  }
  float r[11];
#pragma unroll
  for (int h = 0; h < 6; ++h) {   // p1 = 4t+h, init stage: cd-only (H filter)
    float e = w[h+3]*H0 + w[h+2]*H2 + w[h+1]*H4 + w[h]*H6;
    float o = w[h+3]*H1 + w[h+2]*H3 + w[h+1]*H5 + w[h]*H7;
    r[2*h] = e;
    if (2*h + 1 < 11) r[2*h+1] = o;
  }
  float v[12];
  {
    const float4* p = (const float4*)(cdm + 8 * t);  // 32B-aligned
    float4 a = p[0], b = p[1], c = p[2];
    v[0]=a.x; v[1]=a.y; v[2]=a.z; v[3]=a.w; v[4]=b.x; v[5]=b.y; v[6]=b.z; v[7]=b.w;
    v[8]=c.x; v[9]=c.y; v[10]=c.z; v[11]=c.w;
  }
  float E[8], O[8];
#pragma unroll
  for (int pp = 0; pp < 8; ++pp) {
    E[pp] = r[pp+3]*L0 + r[pp+2]*L2f + r[pp+1]*L4 + r[pp]*L6
          + v[pp+3]*H0 + v[pp+2]*H2  + v[pp+1]*H4 + v[pp]*H6;
    O[pp] = r[pp+3]*L1 + r[pp+2]*L3  + r[pp+1]*L5 + r[pp]*L7
          + v[pp+3]*H1 + v[pp+2]*H3  + v[pp+1]*H5 + v[pp]*H7;
  }
#pragma unroll
  for (int j = 0; j < 4; ++j) {
    const int p2 = 8 * t + 2 * j;
    if (p2 + 1 < np2) {
      *lds4(outl, 4 * t + j) = make_float4(E[2*j], O[2*j], E[2*j+1], O[2*j+1]);
    } else if (p2 < np2) {
      *(float2*)lds4(outl, 4 * t + j) = make_float2(E[2*j], O[2*j]);
    }
  }
}

// rec_L cascade. Stage counts: L2:2 L3:2 L4:2 L5:3 L6:3 L7:4 L8:4 L9:5 = 25
// (was 44 single steps). Chains (lengths after each stage):
//  L2: init<1029> -> 2052 ; final<2051>(cd=d1)
//  L>=3: initpair<NL,NLm1> -> 2*(NLm1-3); then pair/finpair chain:
//  L3: -> final            L4: -> finpair
//  L5: pair<518> final     L6: pair<262> finpair
//  L7: pair<134> pair<518> final    L8: pair<70> pair<262> finpair
//  L9: pair<38> pair<134> pair<518> final
template <int L>
__device__ __forceinline__ void synth2(const float* dr, _Float16* og,
                                       float* s1, float* s2) {
  if constexpr (L == 2) {
    step16<false, true, false, 1029>(nullptr, dr + cDOFF[2], s1, nullptr);
    __syncthreads();
    step16<true, true, true, 2051>(s1, dr + cDOFF[1], nullptr, og);
  } else {
    initpair16<cNL[L], cNL[L - 1]>(dr + cDOFF[L], dr + cDOFF[L - 1], s1);
    __syncthreads();
    if constexpr (L == 3) {
      step16<true, false, true, 2051>(s1, nullptr, nullptr, og);
    } else if constexpr (L == 4) {
      finpair16(s1, og);
    } else if constexpr (L == 5) {
      pair16<518>(s1, s2); __syncthreads();
      step16<true, false, true, 2051>(s2, nullptr, nullptr, og);
    } else if constexpr (L == 6) {
      pair16<262>(s1, s2); __syncthreads();
      finpair16(s2, og);
    } else if constexpr (L == 7) {
      pair16<134>(s1, s2); __syncthreads();
      pair16<518>(s2, s1); __syncthreads();
      step16<true, false, true, 2051>(s1, nullptr, nullptr, og);
    } else if constexpr (L == 8) {
      pair16<70>(s1, s2); __syncthreads();
      pair16<262>(s2, s1); __syncthreads();
      finpair16(s1, og);
    } else {
      pair16<38>(s1, s2); __syncthreads();
      pair16<134>(s1 ? s2 : s2, s1); __syncthreads();
      pair16<518>(s1, s2); __syncthreads();
      step16<true, false, true, 2051>(s2, nullptr, nullptr, og);
    }
  }
}

// ---------------------------------------------------------------------------
// Fused: blocks [0,2048) = analysis rows; blocks [2048, 2048+6144) = W0 cvt.
__global__ __launch_bounds__(WV_THREADS) void wv_analysis_cvt(
    const float* __restrict__ x, float* __restrict__ dG,
    const float* __restrict__ W0, _Float16* __restrict__ Bw) {
  __shared__ float r1[4104];
  __shared__ float r2[2056];
  const int tid = threadIdx.x;

  if (blockIdx.x >= 2048) {  // ---- cvt path ----
    size_t i = ((size_t)(blockIdx.x - 2048) * 256 + tid) * 4;
    int rowc = (int)(i >> 15);
    f16x4v h;
    if (rowc < 181) {
      const float4 v = *(const float4*)(W0 + i);
      h[0] = (_Float16)v.x; h[1] = (_Float16)v.y;
      h[2] = (_Float16)v.z; h[3] = (_Float16)v.w;
    } else {
      h[0] = (_Float16)0.f; h[1] = (_Float16)0.f;
      h[2] = (_Float16)0.f; h[3] = (_Float16)0.f;
    }
    *(f16x4v*)(Bw + i) = h;
    return;
  }

  const int NLa[10]  = {4096, 2051, 1029, 518, 262, 134, 70, 38, 22, 14};
  const int DOFF[10] = {0, 0, 2052, 3084, 3604, 3868, 4004, 4076, 4116, 4140};
  const int LOFF[10] = {0, 0, 1036, 520, 2068, 1040, 2332, 1176, 2404, 1216};
  const int row = blockIdx.x;

  const float4* xr = (const float4*)(x + (size_t)row * 4096);
  for (int i = tid; i < 1024; i += WV_THREADS) ((float4*)r1)[i] = xr[i];
  __syncthreads();

  float* dr = dG + (size_t)row * DROW;
  dwt2(r1, r2, dr + DOFF[1], NLa[0], NLa[1], true);
  __syncthreads();
  const float* ap = r2;
  float* an = r1;
  for (int lev = 2; lev <= 9; ++lev) {
    float* dbuf = ((lev & 1) ? r2 : r1) + LOFF[lev];
    dwt2(ap, an, dbuf, NLa[lev - 1], NLa[lev], lev < 9);
    __syncthreads();
    const float* t = ap; ap = an; an = (float*)t;
  }
  for (int lev = 2; lev <= 9; ++lev) {
    const float* src = ((lev & 1) ? r2 : r1) + LOFF[lev];
    float* dst = dr + DOFF[lev];
    const int n = NLa[lev];
    for (int i = 2 * tid; i + 1 < n; i += 2 * WV_THREADS)
      *(float2*)(dst + i) = *(const float2*)(src + i);
    if ((n & 1) && tid == 0) dst[n - 1] = src[n - 1];
  }
}

// ---------------------------------------------------------------------------
// Synthesis: one block per (row, L=2+blockIdx.y), fused-stage cascades.
__global__ __launch_bounds__(WV_THREADS, 8) void wv_synth(
    const float* __restrict__ dG, _Float16* __restrict__ A) {
  __shared__ alignas(16) float s1[2080];   // 520 float4 slots
  __shared__ alignas(16) float s2[2080];
  const int row = blockIdx.x;
  const float* dr = dG + (size_t)row * DROW;
  _Float16* og = A + (size_t)row * 32768 + (size_t)blockIdx.y * 4096;
  switch (blockIdx.y) {
    case 0: synth2<2>(dr, og, s1, s2); break;
    case 1: synth2<3>(dr, og, s1, s2); break;
    case 2: synth2<4>(dr, og, s1, s2); break;
    case 3: synth2<5>(dr, og, s1, s2); break;
    case 4: synth2<6>(dr, og, s1, s2); break;
    case 5: synth2<7>(dr, og, s1, s2); break;
    case 6: synth2<8>(dr, og, s1, s2); break;
    default: synth2<9>(dr, og, s1, s2); break;
  }
}

// ---------------------------------------------------------------------------
__device__ __forceinline__ void load_lds16(const void* g, void* l) {
  __builtin_amdgcn_global_load_lds((__attribute__((address_space(1))) unsigned int*)g,
                                   (__attribute__((address_space(3))) unsigned int*)l,
                                   16, 0, 0);
}

// C(2048x192) += A(2048x32768,f16) * Bw(192x32768,f16)^T, fp32 split-K
// partials. Grid (16 m, 32 k) = 512 blocks = 2/CU. (Exact R8 form.)
__global__ __launch_bounds__(256, 2) void gemm_kernel(
    const _Float16* __restrict__ A, const _Float16* __restrict__ Bw,
    float* __restrict__ P) {
  __shared__ _Float16 As[128 * 64];  // 16 KB
  __shared__ _Float16 Bs[192 * 64];  // 24 KB
  const int tid = threadIdx.x;
  const int lane = tid & 63;
  const int wave = tid >> 6;
  const int m0 = blockIdx.x * 128;
  const int k_idx = blockIdx.y;
  const int k0 = k_idx * KCHUNK;

  f32x4 acc[2][12];
#pragma unroll
  for (int mt = 0; mt < 2; ++mt)
#pragma unroll
    for (int nt = 0; nt < 12; ++nt) acc[mt][nt] = (f32x4){0.f, 0.f, 0.f, 0.f};

  for (int ks = 0; ks < (KCHUNK >> 6); ++ks) {
    const int kbase = k0 + (ks << 6);
    __syncthreads();
#pragma unroll
    for (int t = 0; t < 4; ++t) {
      int g = ((wave * 4 + t) << 6) + lane;
      int r = g >> 3, cs = g & 7;
      const _Float16* gp = A + (size_t)(m0 + r) * 32768 + kbase + ((cs ^ (r & 7)) << 3);
      load_lds16(gp, (char*)As + (size_t)((wave * 4 + t) << 10));
    }
#pragma unroll
    for (int t = 0; t < 6; ++t) {
      int g = ((wave * 6 + t) << 6) + lane;
      int r = g >> 3, cs = g & 7;
      const _Float16* gp = Bw + (size_t)r * 32768 + kbase + ((cs ^ (r & 7)) << 3);
      load_lds16(gp, (char*)Bs + (size_t)((wave * 6 + t) << 10));
    }
    __syncthreads();
#pragma unroll
    for (int kk = 0; kk < 2; ++kk) {
      const int chunk = kk * 4 + (lane >> 4);
      f16x8 af[2];
#pragma unroll
      for (int mt = 0; mt < 2; ++mt) {
        int r = wave * 32 + mt * 16 + (lane & 15);
        af[mt] = *(const f16x8*)(As + r * 64 + ((chunk ^ (r & 7)) << 3));
      }
#pragma unroll
      for (int nt = 0; nt < 12; ++nt) {
        int rb = nt * 16 + (lane & 15);
        f16x8 bf = *(const f16x8*)(Bs + rb * 64 + ((chunk ^ (rb & 7)) << 3));
        acc[0][nt] = __builtin_amdgcn_mfma_f32_16x16x32_f16(af[0], bf, acc[0][nt], 0, 0, 0);
        acc[1][nt] = __builtin_amdgcn_mfma_f32_16x16x32_f16(af[1], bf, acc[1][nt], 0, 0, 0);
      }
    }
  }
  float* Pp = P + ((size_t)k_idx * 2048 + m0) * 192;
#pragma unroll
  for (int mt = 0; mt < 2; ++mt)
#pragma unroll
    for (int nt = 0; nt < 12; ++nt)
#pragma unroll
      for (int r4 = 0; r4 < 4; ++r4) {
        int rr = wave * 32 + mt * 16 + ((lane >> 4) << 2) + r4;
        int cc = nt * 16 + (lane & 15);
        Pp[(size_t)rr * 192 + cc] = acc[mt][nt][r4];
      }
}

// ---------------------------------------------------------------------------
// P reduce: 4 wave-groups x 8 splits, coalesced; then layers 1..2. (R8 form.)
__global__ __launch_bounds__(256) void mlp_kernel(
    const float* __restrict__ P, const float* __restrict__ b0,
    const float* __restrict__ W1, const float* __restrict__ b1,
    const float* __restrict__ W2, const float* __restrict__ b2,
    float* __restrict__ out) {
  __shared__ float part[4][193];
  __shared__ float h1[192];
  __shared__ float h2[13];
  const int row = blockIdx.x;
  const int t = threadIdx.x;
  const int g = t >> 6;
  const int l = t & 63;

  float a0 = 0.f, a1 = 0.f, a2 = 0.f;
  for (int si = 0; si < NSPLIT / 4; ++si) {
    int s = g + (si << 2);
    const float* Pr = P + ((size_t)s * 2048 + row) * 192;
    a0 += Pr[l]; a1 += Pr[64 + l]; a2 += Pr[128 + l];
  }
  part[g][l] = a0; part[g][64 + l] = a1; part[g][128 + l] = a2;
  __syncthreads();

  if (t < 192) {
    float v = part[0][t] + part[1][t] + part[2][t] + part[3][t];
    h1[t] = (t < 181) ? fmaxf(v + b0[t], 0.f) : 0.f;
  }
  __syncthreads();

#pragma unroll
  for (int r = 0; r < 4; ++r) {
    int j = g + (r << 2);
    if (j < 13) {
      float v = 0.f;
#pragma unroll
      for (int q = 0; q < 3; ++q) {
        int n = l + (q << 6);
        if (n < 181) v += h1[n] * W1[j * 181 + n];
      }
      for (int off = 32; off >= 1; off >>= 1) v += __shfl_down(v, off);
      if (l == 0) h2[j] = fmaxf(v + b1[j], 0.f);
    }
  }
  __syncthreads();

  if (t < 10) {
    float c = b2[t];
#pragma unroll
    for (int j = 0; j < 13; ++j) c += h2[j] * W2[t * 13 + j];
    out[(size_t)row * 10 + t] = c;
  }
}

// ---------------------------------------------------------------------------
extern "C" void kernel_launch(void* const* d_in, const int* in_sizes, int n_in,
                              void* d_out, int out_size, void* d_ws, size_t ws_size,
                              hipStream_t stream) {
  const float* x1 = (const float*)d_in[0];
  const float* W0 = (const float*)d_in[3];
  const float* b0 = (const float*)d_in[4];
  const float* W1 = (const float*)d_in[5];
  const float* b1 = (const float*)d_in[6];
  const float* W2 = (const float*)d_in[7];
  const float* b2 = (const float*)d_in[8];
  float* out = (float*)d_out;

  char* ws = (char*)d_ws;
  const size_t A_BYTES = (size_t)2048 * 32768 * 2;
  const size_t B_BYTES = (size_t)192 * 32768 * 2;
  _Float16* Afeat = (_Float16*)ws;
  _Float16* Bw = (_Float16*)(ws + A_BYTES);
  // D (2048*4160*4 = 34 MB) aliases P (50 MB): D dead before gemm writes P.
  float* Dq = (float*)(ws + A_BYTES + B_BYTES);
  float* P = (float*)(ws + A_BYTES + B_BYTES);

  wv_analysis_cvt<<<2048 + 6144, WV_THREADS, 0, stream>>>(x1, Dq, W0, Bw);
  dim3 sg(2048, 8);
  wv_synth<<<sg, WV_THREADS, 0, stream>>>(Dq, Afeat);
  dim3 gg(16, NSPLIT);
  gemm_kernel<<<gg, 256, 0, stream>>>(Afeat, Bw, P);
  mlp_kernel<<<2048, 256, 0, stream>>>(P, b0, W1, b1, W2, b2, out);
}